// Round 17
// baseline (141.798 us; speedup 1.0000x reference)
//
#include <hip/hip_runtime.h>
#include <math.h>

typedef unsigned int u32;
typedef unsigned long long u64;
typedef unsigned short ushortT;
typedef __attribute__((ext_vector_type(8))) short short8;
typedef __attribute__((ext_vector_type(4))) float f32x4;

#define Qn    900
#define Bn    16
#define Hn    256
#define NBINS 36
#define NB2   1296
#define T64   64
#define NTILE64 15   // ceil(900/64)
#define NP64  120    // tile pairs ti<=tj
#define NSLOT 6      // ceil(NB2/256) per-thread tail slots
#define PS    ((size_t)Bn * Qn * Hn)   // bf16 plane stride (elements)
#define TWO_PI_F 6.2831853071795864769f
#define PI_F     3.1415926535897932385f
#define HALF_PI_F 1.5707963267948966f
#define BIN_SIZE_F (TWO_PI_F / 36.0f)
#define BIGV 1e9f

__device__ __forceinline__ u32 fkey(float f) {
    u32 u = __float_as_uint(f);
    return (u & 0x80000000u) ? ~u : (u | 0x80000000u);
}
__device__ __forceinline__ float unfkey(u32 k) {
    u32 u = (k & 0x80000000u) ? (k ^ 0x80000000u) : ~k;
    return __uint_as_float(u);
}
__device__ __forceinline__ float circdist(float a, float b) {
    float diff = fabsf(a - b);
    return fminf(fminf(diff, TWO_PI_F - diff), HALF_PI_F);
}
__device__ __forceinline__ void ins4(float* t4, float v) {
    if (v > t4[3]) {
        if (v > t4[0]) { t4[3]=t4[2]; t4[2]=t4[1]; t4[1]=t4[0]; t4[0]=v; }
        else if (v > t4[1]) { t4[3]=t4[2]; t4[2]=t4[1]; t4[1]=v; }
        else if (v > t4[2]) { t4[3]=t4[2]; t4[2]=v; }
        else t4[3]=v;
    }
}
__device__ __forceinline__ void ins2(float& m1, float& m2, float x) {
    if (x > m1) { m2 = m1; m1 = x; }
    else if (x > m2) m2 = x;
}
// round-to-nearest-even f32 -> bf16, also returns the value it represents
__device__ __forceinline__ ushortT bf16rne(float x, float& back) {
    u32 u = __float_as_uint(x);
    u32 r = u + 0x7FFFu + ((u >> 16) & 1u);
    ushortT h = (ushortT)(r >> 16);
    back = __uint_as_float(((u32)h) << 16);
    return h;
}
// async global->LDS, 16B per lane. HW semantics: wave-uniform base + lane*16.
__device__ __forceinline__ void gl_lds16(const ushortT* g, ushortT* l) {
    __builtin_amdgcn_global_load_lds(
        (const __attribute__((address_space(1))) unsigned int*)g,
        (__attribute__((address_space(3))) unsigned int*)l,
        16, 0, 0);
}

// ---- block helpers for 256 threads (4 waves) --------------------------------
__device__ __forceinline__ int bSumI(int v, volatile int* red) {
    #pragma unroll
    for (int off = 32; off >= 1; off >>= 1) v += __shfl_xor(v, off, 64);
    int w = threadIdx.x >> 6;
    if ((threadIdx.x & 63) == 0) red[w] = v;
    __syncthreads();
    int r = red[0] + red[1] + red[2] + red[3];
    __syncthreads();
    return r;
}
__device__ __forceinline__ float bSumF(float v, volatile float* red) {
    #pragma unroll
    for (int off = 32; off >= 1; off >>= 1) v += __shfl_xor(v, off, 64);
    int w = threadIdx.x >> 6;
    if ((threadIdx.x & 63) == 0) red[w] = v;
    __syncthreads();
    float r = red[0] + red[1] + red[2] + red[3];
    __syncthreads();
    return r;
}
__device__ __forceinline__ u32 bMinU(u32 v, volatile u32* red) {
    #pragma unroll
    for (int off = 32; off >= 1; off >>= 1) {
        u32 o = (u32)__shfl_xor((int)v, off, 64);
        v = v < o ? v : o;
    }
    int w = threadIdx.x >> 6;
    if ((threadIdx.x & 63) == 0) red[w] = v;
    __syncthreads();
    u32 r = red[0];
    if (red[1] < r) r = red[1];
    if (red[2] < r) r = red[2];
    if (red[3] < r) r = red[3];
    __syncthreads();
    return r;
}
__device__ __forceinline__ void bTop2(float m1, float m2, volatile float* red2,
                                      float& o1, float& o2) {
    #pragma unroll
    for (int off = 32; off >= 1; off >>= 1) {
        float a1 = __shfl_xor(m1, off, 64);
        float a2 = __shfl_xor(m2, off, 64);
        ins2(m1, m2, a1); ins2(m1, m2, a2);
    }
    int w = threadIdx.x >> 6;
    if ((threadIdx.x & 63) == 0) { red2[w * 2] = m1; red2[w * 2 + 1] = m2; }
    __syncthreads();
    float r1 = red2[0], r2 = red2[1];
    #pragma unroll
    for (int ww = 1; ww < 4; ww++) { ins2(r1, r2, red2[ww * 2]); ins2(r1, r2, red2[ww * 2 + 1]); }
    __syncthreads();
    o1 = r1; o2 = r2;
}
// rank-p key over compacted set in LDS (m up to NB2; typically tiny)
__device__ u32 selRank(const u32* ckeys, int m, int p, volatile u32* redU) {
    u32 best = 0xFFFFFFFFu;
    for (int base = 0; base < m; base += 256) {
        int idx = base + (int)threadIdx.x;
        if (idx < m) {
            u32 k = ckeys[idx];
            int c = 0;
            for (int j = 0; j < m; j++) c += (ckeys[j] <= k);
            if (c >= p + 1 && k < best) best = k;
        }
    }
    return bMinU(best, redU);
}
// masked quantile at q=1-1/(n+1): pos = n-2 + 2/(n+1) -> lo=n-2, hi=n-1,
// i.e. interpolation between 2nd-max and max (same float arithmetic as ref).
__device__ __forceinline__ float quantTop2(float top1, float top2, int n) {
    float nf = (float)n;
    float qq = 1.f - 1.f / (nf + 1.f);
    float pos = qq * fmaxf(nf - 1.f, 0.f);
    int lo = (int)floorf(pos), hi = (int)ceilf(pos);
    float frac = pos - (float)lo;
    float slo = (lo >= n - 1) ? top1 : top2;
    float shi = (hi >= n - 1) ? top1 : top2;
    return slo + (shi - slo) * frac;
}

// ---------------- K0: angles, bins, counting-sort by bin (1 block / batch) ----
__global__ void k0_sort(const float* __restrict__ pa, float* __restrict__ anglesO,
                        int* __restrict__ binsO, int* __restrict__ sortPos,
                        int* __restrict__ origIdx, int* __restrict__ binSorted,
                        u64* __restrict__ segBest, u32* __restrict__ bcnt) {
    int b = blockIdx.x, t = threadIdx.x;
    __shared__ int hist[NBINS], offs[NBINS], offs2[NBINS];
    if (t < NBINS) hist[t] = 0;
    // counters: one per 64B cache line (stride 16 u32); [b*16] per batch,
    // [Bn*16] final-combine. Only block 0 initializes.
    if (b == 0 && t < (Bn + 1)) bcnt[t * 16] = 0u;
    for (int s = t; s < NB2; s += 256) segBest[(size_t)b * NB2 + s] = 0ULL;
    __syncthreads();
    for (int q = t; q < Qn; q += blockDim.x) {
        float x = pa[(b * Qn + q) * 2 + 0];
        float y = pa[(b * Qn + q) * 2 + 1];
        float a = atan2f(y, x);
        if (a < 0.f) a += TWO_PI_F;
        int bin = (int)(a / BIN_SIZE_F);
        bin = bin < 0 ? 0 : (bin > NBINS - 1 ? NBINS - 1 : bin);
        anglesO[b * Qn + q] = a;
        binsO[b * Qn + q] = bin;
        atomicAdd(&hist[bin], 1);
    }
    __syncthreads();
    if (t == 0) { int s = 0; for (int i = 0; i < NBINS; i++) { offs[i] = s; s += hist[i]; } }
    __syncthreads();
    if (t < NBINS) offs2[t] = offs[t];
    __syncthreads();
    for (int q = t; q < Qn; q += blockDim.x) {
        int bin = binsO[b * Qn + q];
        int pos = atomicAdd(&offs2[bin], 1);
        sortPos[b * Qn + q] = pos;
        origIdx[b * Qn + pos] = q;
        binSorted[b * Qn + pos] = bin;
    }
}

// ---------------- K1: fused+normalize, split into 2 bf16 planes (sorted) -----
__global__ void k1_norm(const float4* __restrict__ qf, const float4* __restrict__ W,
                        const int* __restrict__ binsO, const int* __restrict__ sortPos,
                        ushortT* __restrict__ nqB) {
    int b = blockIdx.x;
    int w = threadIdx.x >> 6, lane = threadIdx.x & 63;
    int q = blockIdx.y * 4 + w;  // grid.y = 225, 900 = 4*225
    int bin = binsO[b * Qn + q];
    float4 v = qf[(size_t)(b * Qn + q) * (Hn / 4) + lane];
    float4 wv = W[(size_t)bin * (Hn / 4) + lane];
    v.x += wv.x; v.y += wv.y; v.z += wv.z; v.w += wv.w;
    float ss = v.x * v.x + v.y * v.y + v.z * v.z + v.w * v.w;
    #pragma unroll
    for (int off = 32; off >= 1; off >>= 1) ss += __shfl_xor(ss, off, 64);
    float sc = 1.f / fmaxf(sqrtf(ss), 1e-12f);
    float xs[4] = {v.x * sc, v.y * sc, v.z * sc, v.w * sc};
    ushort4 p0, p1;
    ushortT* h0 = (ushortT*)&p0; ushortT* h1 = (ushortT*)&p1;
    #pragma unroll
    for (int c = 0; c < 4; c++) {
        float f0, f1;
        h0[c] = bf16rne(xs[c], f0);
        float r1 = xs[c] - f0;
        h1[c] = bf16rne(r1, f1);
    }
    int sp = sortPos[b * Qn + q];
    size_t base = ((size_t)(b * Qn + sp)) * Hn + lane * 4;
    *(ushort4*)(nqB + 0 * PS + base) = p0;
    *(ushort4*)(nqB + 1 * PS + base) = p1;
}

// ---------------- K2: MFMA pair-sim GEMM + segment argmax + fused k3 tail ----
// R16 lesson: capacity (4 blocks/CU) was BELOW work supply (1920/256 = 7.5
// blocks/CU) -> grid ran as ~2 sequential block-waves. Resources allow 8:
// LDS 17.9KB x 8 = 143KB < 160KB, VGPR 32 <= 64 budget. (256,8) makes the
// grid nearly fully co-resident: better barrier-drain hiding + tails overlap.
// Everything else identical to R16 (XCD-local decode, per-line counters,
// RELAXED per-batch counter, register-resident tail).
__global__ __launch_bounds__(256, 8) void k2_gemm(
        const ushortT* __restrict__ nqB, const int* __restrict__ binSorted,
        const int* __restrict__ origIdx, u64* __restrict__ segBest,
        float* __restrict__ topCand, const float* __restrict__ anglesO,
        float* __restrict__ batchRes, u32* __restrict__ bcnt,
        float* __restrict__ out) {
    __shared__ __align__(16) union Sh {
        ushortT stage[4 * 2048];   // 16 KB during K-loop
        u64     segLds[NB2];       // 10.4 KB during emission
        u32     ckeys[NB2];        // 5.2 KB during tail median (disjoint)
    } sh;
    __shared__ int rbins[T64], cbins[T64], rois[T64], cois[T64];
    __shared__ float t4w[16];
    __shared__ int redI[4];
    __shared__ float redF[4];
    __shared__ u32 redU[4];
    __shared__ float red2[8];
    __shared__ int mcnt, shLast;
    __shared__ float sth2;

    int lin = blockIdx.x;
    int xcd = lin & 7;
    int slot = lin >> 3;                 // 0..239
    int b = xcd * 2 + (slot >= NP64 ? 1 : 0);
    int tp = (slot >= NP64) ? slot - NP64 : slot;
    int ti = 0, rem = tp;
    while (rem >= NTILE64 - ti) { rem -= NTILE64 - ti; ti++; }
    int tj = ti + rem;
    int rowBase = ti * T64, colBase = tj * T64;
    int t = threadIdx.x;
    int w = t >> 6, lane = t & 63;
    int wrow = w >> 1, wcol = w & 1;
    int lq = lane >> 4, lm = lane & 15;

    if (t < T64) {
        int sr = rowBase + t, sc = colBase + t;
        rbins[t] = (sr < Qn) ? binSorted[b * Qn + sr] : 0;
        rois[t]  = (sr < Qn) ? origIdx[b * Qn + sr] : 0;
        cbins[t] = (sc < Qn) ? binSorted[b * Qn + sc] : 0;
        cois[t]  = (sc < Qn) ? origIdx[b * Qn + sc] : 0;
    }

    f32x4 acc[2][2];
    #pragma unroll
    for (int i = 0; i < 2; i++)
        #pragma unroll
        for (int j = 0; j < 2; j++) acc[i][j] = (f32x4){0.f, 0.f, 0.f, 0.f};

    u32 goff[4];
    int loff[4];
    #pragma unroll
    for (int i = 0; i < 4; i++) {
        int p = i & 1;                       // plane
        int sideB = i >> 1;                  // 0 = A rows, 1 = B rows
        int row = t >> 2;
        int udata = (t & 3) ^ ((t >> 3) & 3);
        int gq = (sideB ? colBase : rowBase) + row;
        if (gq >= Qn) gq = Qn - 1;
        goff[i] = (u32)(p * (u32)PS) + (u32)(b * Qn + gq) * Hn + (u32)(udata * 8);
        loff[i] = i * 2048 + t * 8;
    }
    int aswz = (lq ^ ((lm >> 1) & 3)) * 8;   // swizzled 16B-unit offset

    for (int kc = 0; kc < Hn; kc += 32) {
        #pragma unroll
        for (int i = 0; i < 4; i++)
            gl_lds16(nqB + goff[i] + kc, &sh.stage[loff[i]]);
        __syncthreads();   // vmcnt(0) drain before barrier

        short8 af[2][2];
        #pragma unroll
        for (int p = 0; p < 2; p++)
            #pragma unroll
            for (int mt = 0; mt < 2; mt++)
                af[p][mt] = *(const short8*)&sh.stage[p * 2048 + (wrow * 32 + mt * 16 + lm) * 32 + aswz];

        #pragma unroll
        for (int nt = 0; nt < 2; nt++) {
            int coff = (wcol * 32 + nt * 16 + lm) * 32 + aswz;
            short8 b0 = *(const short8*)&sh.stage[2 * 2048 + coff];
            short8 b1 = *(const short8*)&sh.stage[3 * 2048 + coff];
            #pragma unroll
            for (int mt = 0; mt < 2; mt++) {
                f32x4 c = acc[mt][nt];
                c = __builtin_amdgcn_mfma_f32_16x16x32_bf16(af[0][mt], b0, c, 0, 0, 0);
                c = __builtin_amdgcn_mfma_f32_16x16x32_bf16(af[0][mt], b1, c, 0, 0, 0);
                c = __builtin_amdgcn_mfma_f32_16x16x32_bf16(af[1][mt], b0, c, 0, 0, 0);
                c = __builtin_amdgcn_mfma_f32_16x16x32_bf16(af[1][mt], b1, c, 0, 0, 0);
                acc[mt][nt] = c;
            }
        }
        __syncthreads();   // frag reads done before next chunk's DMA writes
    }

    // ---- repurpose stage memory as segLds; zero it ----
    for (int s = t; s < NB2; s += 256) sh.segLds[s] = 0ULL;
    __syncthreads();

    // ---- emission: C/D layout col=lm, row=lq*4+reg (m89-verified) ----
    float t4[4] = {-3e38f, -3e38f, -3e38f, -3e38f};
    int curSeg = -1; u64 curBest = 0ULL;
    #pragma unroll
    for (int mt = 0; mt < 2; mt++) {
        #pragma unroll
        for (int r = 0; r < 4; r++) {
            int lrr = wrow * 32 + mt * 16 + lq * 4 + r;
            int sr = rowBase + lrr;
            int bi = rbins[lrr], io = rois[lrr];
            #pragma unroll
            for (int nt = 0; nt < 2; nt++) {
                int lcc = wcol * 32 + nt * 16 + lm;
                int sc = colBase + lcc;
                bool ok = (sr < Qn) && (sc < Qn) && (sr < sc);
                if (ok) {
                    float v = acc[mt][nt][r];
                    ins4(t4, v);
                    int bj = cbins[lcc], jo = cois[lcc];
                    int bmin = bi < bj ? bi : bj, bmax = bi < bj ? bj : bi;
                    int seg = bmin * NBINS + bmax;
                    int imin = io < jo ? io : jo, jmax = io < jo ? jo : io;
                    u64 packed = ((u64)fkey(v) << 32) | (u32)(~(((u32)imin << 10) | (u32)jmax));
                    if (seg == curSeg) { if (packed > curBest) curBest = packed; }
                    else {
                        if (curSeg >= 0) atomicMax(&sh.segLds[curSeg], curBest);
                        curSeg = seg; curBest = packed;
                    }
                }
            }
        }
    }
    if (curSeg >= 0) atomicMax(&sh.segLds[curSeg], curBest);

    // wave-level top4 shuffle merge
    #pragma unroll
    for (int off = 32; off >= 1; off >>= 1) {
        float o0 = __shfl_xor(t4[0], off, 64);
        float o1 = __shfl_xor(t4[1], off, 64);
        float o2 = __shfl_xor(t4[2], off, 64);
        float o3 = __shfl_xor(t4[3], off, 64);
        ins4(t4, o0); ins4(t4, o1); ins4(t4, o2); ins4(t4, o3);
    }
    if (lane == 0) {
        t4w[w * 4 + 0] = t4[0]; t4w[w * 4 + 1] = t4[1];
        t4w[w * 4 + 2] = t4[2]; t4w[w * 4 + 3] = t4[3];
    }
    __syncthreads();

    for (int s = t; s < NB2; s += 256) {
        u64 v = sh.segLds[s];
        if (v) atomicMax(&segBest[(size_t)b * NB2 + s], v);
    }
    if (t == 0) {
        #pragma unroll
        for (int ww = 1; ww < 4; ww++) {
            ins4(t4, t4w[ww * 4 + 0]); ins4(t4, t4w[ww * 4 + 1]);
            ins4(t4, t4w[ww * 4 + 2]); ins4(t4, t4w[ww * 4 + 3]);
        }
        float* dst = topCand + (size_t)(b * NP64 + tp) * 4;
        #pragma unroll
        for (int c = 0; c < 4; c++)
            __hip_atomic_store(&dst[c], t4[c], __ATOMIC_RELAXED, __HIP_MEMORY_SCOPE_AGENT);
    }

    // ---- per-batch completion; last block runs the scalar tail inline ----
    __syncthreads();   // drains vmcnt(0): segBest atomics + topCand stores done
    if (t == 0) {
        u32 done = __hip_atomic_fetch_add(&bcnt[b * 16], 1u, __ATOMIC_RELAXED,
                                          __HIP_MEMORY_SCOPE_AGENT);
        shLast = (done == NP64 - 1) ? 1 : 0;
    }
    __syncthreads();
    if (!shLast) return;

    // ====== inline k3 tail: register-resident (NSLOT=6 segments/thread) ======
    float rval[NSLOT], rd[NSLOT];
    u32 rcode[NSLOT];
    bool rvalid[NSLOT], rmF[NSLOT];
    #pragma unroll
    for (int k = 0; k < NSLOT; k++) {
        int s = t + k * 256;
        rvalid[k] = false; rval[k] = 0.f; rd[k] = 0.f; rcode[k] = 0u; rmF[k] = false;
        if (s < NB2) {
            u64 p = __hip_atomic_load(&segBest[(size_t)b * NB2 + s],
                                      __ATOMIC_RELAXED, __HIP_MEMORY_SCOPE_AGENT);
            if (p != 0ULL) {
                rvalid[k] = true;
                rval[k] = unfkey((u32)(p >> 32));
                rcode[k] = ~((u32)p);
                int i = (rcode[k] >> 10) & 1023, j = rcode[k] & 1023;
                float ai = anglesO[b * Qn + i], aj = anglesO[b * Qn + j];
                rd[k] = circdist(ai, aj);
            }
        }
    }

    // S + top2 of valid sims -> thr
    int Sv = 0;
    float m1 = -3e38f, m2 = -3e38f;
    #pragma unroll
    for (int k = 0; k < NSLOT; k++)
        if (rvalid[k]) { Sv++; ins2(m1, m2, rval[k]); }
    int S = bSumI(Sv, redI);
    float top1, top2v;
    bTop2(m1, m2, red2, top1, top2v);
    float thr = (S == 0) ? BIGV : quantTop2(top1, top2v, S);

    int c1v = 0;
    #pragma unroll
    for (int k = 0; k < NSLOT; k++)
        if (rvalid[k] && rval[k] > thr) c1v++;
    int c1 = bSumI(c1v, redI);

    // th2 = 4th-largest pair sim (wave 0 merges all blocks' top4s)
    if (t < 64) {
        float t4l[4] = {-3e38f, -3e38f, -3e38f, -3e38f};
        for (int i = t; i < NP64 * 4; i += 64)
            ins4(t4l, __hip_atomic_load(&topCand[(size_t)b * NP64 * 4 + i],
                                        __ATOMIC_RELAXED, __HIP_MEMORY_SCOPE_AGENT));
        #pragma unroll
        for (int off = 32; off >= 1; off >>= 1) {
            float o0 = __shfl_xor(t4l[0], off, 64);
            float o1 = __shfl_xor(t4l[1], off, 64);
            float o2 = __shfl_xor(t4l[2], off, 64);
            float o3 = __shfl_xor(t4l[3], off, 64);
            ins4(t4l, o0); ins4(t4l, o1); ins4(t4l, o2); ins4(t4l, o3);
        }
        if (t == 0) sth2 = t4l[3];
    }
    __syncthreads();
    float th2 = sth2;

    bool use_fb = (c1 < 2);
    int cv = 0;
    #pragma unroll
    for (int k = 0; k < NSLOT; k++) {
        bool mF = use_fb ? (rvalid[k] && rval[k] >= th2)
                         : (rvalid[k] && rval[k] > thr);
        rmF[k] = mF;
        cv += mF ? 1 : 0;
    }
    int cnt = bSumI(cv, redI);

    // median of masked d: compact into LDS ckeys + rank select
    if (t == 0) mcnt = 0;
    __syncthreads();
    #pragma unroll
    for (int k = 0; k < NSLOT; k++) {
        bool pred = rmF[k];
        u32 key = fkey(rd[k]);
        u64 bal = __ballot(pred);
        int prefix = __popcll(bal & ((1ULL << lane) - 1ULL));
        int tot = __popcll(bal);
        int base = 0;
        if (lane == 0) base = tot ? atomicAdd(&mcnt, tot) : 0;
        base = __shfl(base, 0, 64);
        if (pred) sh.ckeys[base + prefix] = key;
    }
    __syncthreads();
    int m2c = mcnt;

    float med;
    if (cnt == 0) med = BIGV;
    else {
        int midx = (cnt - 1) >> 1;
        med = unfkey(selRank(sh.ckeys, m2c, midx, redU));
    }
    float alpha = fminf(fmaxf(med, PI_F / (float)NBINS), HALF_PI_F);

    // coop stats + comp count/top2 in one pass (angles reloaded from L2)
    int ncoopv = 0, ncompv = 0; float coopv = 0.f;
    float c1m = -3e38f, c2m = -3e38f;
    #pragma unroll
    for (int k = 0; k < NSLOT; k++) {
        if (!rmF[k]) continue;
        if (rd[k] <= alpha) {
            ncoopv++;
            int i = (rcode[k] >> 10) & 1023, j = rcode[k] & 1023;
            float ai = anglesO[b * Qn + i], aj = anglesO[b * Qn + j];
            float mm = atan2f((sinf(ai) + sinf(aj)) * 0.5f, (cosf(ai) + cosf(aj)) * 0.5f);
            float d1 = circdist(ai, mm), d2 = circdist(aj, mm);
            coopv += d1 * d1 + d2 * d2;
        } else {
            ncompv++;
            ins2(c1m, c2m, rval[k]);
        }
    }
    int ncoop = bSumI(ncoopv, redI);
    float coopSum = bSumF(coopv, redF);
    int ncomp = bSumI(ncompv, redI);
    float ct1, ct2;
    bTop2(c1m, c2m, red2, ct1, ct2);
    float margin = (ncomp == 0) ? BIGV : quantTop2(ct1, ct2, ncomp);

    float compv = 0.f;
    #pragma unroll
    for (int k = 0; k < NSLOT; k++) {
        if (rmF[k] && rd[k] > alpha) {
            float viol = fmaxf(rval[k] - margin, 0.f);
            compv += viol * viol;
        }
    }
    float compSum = bSumF(compv, redF);

    // final combine: last-finished batch reduces all batchRes. ACQ_REL here is
    // fine — only 16 executions total (vs 1920 for the per-block counter).
    if (t == 0) {
        float r0 = coopSum / (float)(ncoop > 1 ? ncoop : 1);
        float r1 = compSum / (float)(ncomp > 1 ? ncomp : 1);
        float r2 = cnt > 0 ? 1.f : 0.f;
        __hip_atomic_store(&batchRes[b * 3 + 0], r0, __ATOMIC_RELAXED, __HIP_MEMORY_SCOPE_AGENT);
        __hip_atomic_store(&batchRes[b * 3 + 1], r1, __ATOMIC_RELAXED, __HIP_MEMORY_SCOPE_AGENT);
        __hip_atomic_store(&batchRes[b * 3 + 2], r2, __ATOMIC_RELAXED, __HIP_MEMORY_SCOPE_AGENT);
        u32 doneB = __hip_atomic_fetch_add(&bcnt[Bn * 16], 1u, __ATOMIC_ACQ_REL,
                                           __HIP_MEMORY_SCOPE_AGENT);
        if (doneB == Bn - 1) {
            float cs = 0.f, ps = 0.f, vs = 0.f;
            for (int bb = 0; bb < Bn; bb++) {
                cs += __hip_atomic_load(&batchRes[bb * 3 + 0], __ATOMIC_RELAXED, __HIP_MEMORY_SCOPE_AGENT);
                ps += __hip_atomic_load(&batchRes[bb * 3 + 1], __ATOMIC_RELAXED, __HIP_MEMORY_SCOPE_AGENT);
                vs += __hip_atomic_load(&batchRes[bb * 3 + 2], __ATOMIC_RELAXED, __HIP_MEMORY_SCOPE_AGENT);
            }
            float denom = fmaxf(vs, 1.f);
            out[0] = cs / denom;
            out[1] = ps / denom;
        }
    }
}

extern "C" void kernel_launch(void* const* d_in, const int* in_sizes, int n_in,
                              void* d_out, int out_size, void* d_ws, size_t ws_size,
                              hipStream_t stream) {
    (void)in_sizes; (void)n_in; (void)out_size; (void)ws_size;
    const float* qf = (const float*)d_in[0];
    const float* pa = (const float*)d_in[1];
    const float* W  = (const float*)d_in[2];
    float* out = (float*)d_out;

    char* ws = (char*)d_ws;
    size_t off = 0;
    ushortT* nqB = (ushortT*)(ws + off);  off += 2 * PS * 2;                 // 14.7 MB
    float* anglesO = (float*)(ws + off);  off += (size_t)Bn * Qn * 4;
    int* binsO = (int*)(ws + off);        off += (size_t)Bn * Qn * 4;
    int* sortPos = (int*)(ws + off);      off += (size_t)Bn * Qn * 4;
    int* origIdx = (int*)(ws + off);      off += (size_t)Bn * Qn * 4;
    int* binSorted = (int*)(ws + off);    off += (size_t)Bn * Qn * 4;
    u64* segBest = (u64*)(ws + off);      off += (size_t)Bn * NB2 * 8;
    float* topCand = (float*)(ws + off);  off += (size_t)Bn * NP64 * 4 * 4;
    float* batchRes = (float*)(ws + off); off += (size_t)Bn * 3 * 4;
    u32* bcnt = (u32*)(ws + off);         off += (Bn + 1) * 64;   // 1 line each

    k0_sort<<<Bn, 256, 0, stream>>>(pa, anglesO, binsO, sortPos, origIdx, binSorted,
                                    segBest, bcnt);
    k1_norm<<<dim3(Bn, 225), 256, 0, stream>>>((const float4*)qf, (const float4*)W,
                                               binsO, sortPos, nqB);
    k2_gemm<<<NP64 * Bn, 256, 0, stream>>>(nqB, binSorted, origIdx, segBest, topCand,
                                           anglesO, batchRes, bcnt, out);
}

// Round 18
// 124.778 us; speedup vs baseline: 1.1364x; 1.1364x over previous
//
#include <hip/hip_runtime.h>
#include <math.h>

typedef unsigned int u32;
typedef unsigned long long u64;
typedef unsigned short ushortT;
typedef __attribute__((ext_vector_type(8))) short short8;
typedef __attribute__((ext_vector_type(4))) float f32x4;

#define Qn    900
#define Bn    16
#define Hn    256
#define NBINS 36
#define NB2   1296
#define T64   64
#define NTILE64 15   // ceil(900/64)
#define NP64  120    // tile pairs ti<=tj
#define NSLOT 6      // ceil(NB2/256) per-thread tail slots
#define PS    ((size_t)Bn * Qn * Hn)   // bf16 plane stride (elements)
#define TWO_PI_F 6.2831853071795864769f
#define PI_F     3.1415926535897932385f
#define HALF_PI_F 1.5707963267948966f
#define BIN_SIZE_F (TWO_PI_F / 36.0f)
#define BIGV 1e9f

__device__ __forceinline__ u32 fkey(float f) {
    u32 u = __float_as_uint(f);
    return (u & 0x80000000u) ? ~u : (u | 0x80000000u);
}
__device__ __forceinline__ float unfkey(u32 k) {
    u32 u = (k & 0x80000000u) ? (k ^ 0x80000000u) : ~k;
    return __uint_as_float(u);
}
__device__ __forceinline__ float circdist(float a, float b) {
    float diff = fabsf(a - b);
    return fminf(fminf(diff, TWO_PI_F - diff), HALF_PI_F);
}
__device__ __forceinline__ void ins4(float* t4, float v) {
    if (v > t4[3]) {
        if (v > t4[0]) { t4[3]=t4[2]; t4[2]=t4[1]; t4[1]=t4[0]; t4[0]=v; }
        else if (v > t4[1]) { t4[3]=t4[2]; t4[2]=t4[1]; t4[1]=v; }
        else if (v > t4[2]) { t4[3]=t4[2]; t4[2]=v; }
        else t4[3]=v;
    }
}
__device__ __forceinline__ void ins2(float& m1, float& m2, float x) {
    if (x > m1) { m2 = m1; m1 = x; }
    else if (x > m2) m2 = x;
}
// round-to-nearest-even f32 -> bf16, also returns the value it represents
__device__ __forceinline__ ushortT bf16rne(float x, float& back) {
    u32 u = __float_as_uint(x);
    u32 r = u + 0x7FFFu + ((u >> 16) & 1u);
    ushortT h = (ushortT)(r >> 16);
    back = __uint_as_float(((u32)h) << 16);
    return h;
}
// async global->LDS, 16B per lane. HW semantics: wave-uniform base + lane*16.
__device__ __forceinline__ void gl_lds16(const ushortT* g, ushortT* l) {
    __builtin_amdgcn_global_load_lds(
        (const __attribute__((address_space(1))) unsigned int*)g,
        (__attribute__((address_space(3))) unsigned int*)l,
        16, 0, 0);
}

// ---- block helpers for 256 threads (4 waves) --------------------------------
__device__ __forceinline__ int bSumI(int v, volatile int* red) {
    #pragma unroll
    for (int off = 32; off >= 1; off >>= 1) v += __shfl_xor(v, off, 64);
    int w = threadIdx.x >> 6;
    if ((threadIdx.x & 63) == 0) red[w] = v;
    __syncthreads();
    int r = red[0] + red[1] + red[2] + red[3];
    __syncthreads();
    return r;
}
__device__ __forceinline__ float bSumF(float v, volatile float* red) {
    #pragma unroll
    for (int off = 32; off >= 1; off >>= 1) v += __shfl_xor(v, off, 64);
    int w = threadIdx.x >> 6;
    if ((threadIdx.x & 63) == 0) red[w] = v;
    __syncthreads();
    float r = red[0] + red[1] + red[2] + red[3];
    __syncthreads();
    return r;
}
__device__ __forceinline__ u32 bMinU(u32 v, volatile u32* red) {
    #pragma unroll
    for (int off = 32; off >= 1; off >>= 1) {
        u32 o = (u32)__shfl_xor((int)v, off, 64);
        v = v < o ? v : o;
    }
    int w = threadIdx.x >> 6;
    if ((threadIdx.x & 63) == 0) red[w] = v;
    __syncthreads();
    u32 r = red[0];
    if (red[1] < r) r = red[1];
    if (red[2] < r) r = red[2];
    if (red[3] < r) r = red[3];
    __syncthreads();
    return r;
}
__device__ __forceinline__ void bTop2(float m1, float m2, volatile float* red2,
                                      float& o1, float& o2) {
    #pragma unroll
    for (int off = 32; off >= 1; off >>= 1) {
        float a1 = __shfl_xor(m1, off, 64);
        float a2 = __shfl_xor(m2, off, 64);
        ins2(m1, m2, a1); ins2(m1, m2, a2);
    }
    int w = threadIdx.x >> 6;
    if ((threadIdx.x & 63) == 0) { red2[w * 2] = m1; red2[w * 2 + 1] = m2; }
    __syncthreads();
    float r1 = red2[0], r2 = red2[1];
    #pragma unroll
    for (int ww = 1; ww < 4; ww++) { ins2(r1, r2, red2[ww * 2]); ins2(r1, r2, red2[ww * 2 + 1]); }
    __syncthreads();
    o1 = r1; o2 = r2;
}
// rank-p key over compacted set in LDS (m up to NB2; typically tiny)
__device__ u32 selRank(const u32* ckeys, int m, int p, volatile u32* redU) {
    u32 best = 0xFFFFFFFFu;
    for (int base = 0; base < m; base += 256) {
        int idx = base + (int)threadIdx.x;
        if (idx < m) {
            u32 k = ckeys[idx];
            int c = 0;
            for (int j = 0; j < m; j++) c += (ckeys[j] <= k);
            if (c >= p + 1 && k < best) best = k;
        }
    }
    return bMinU(best, redU);
}
// masked quantile at q=1-1/(n+1): pos = n-2 + 2/(n+1) -> lo=n-2, hi=n-1,
// i.e. interpolation between 2nd-max and max (same float arithmetic as ref).
__device__ __forceinline__ float quantTop2(float top1, float top2, int n) {
    float nf = (float)n;
    float qq = 1.f - 1.f / (nf + 1.f);
    float pos = qq * fmaxf(nf - 1.f, 0.f);
    int lo = (int)floorf(pos), hi = (int)ceilf(pos);
    float frac = pos - (float)lo;
    float slo = (lo >= n - 1) ? top1 : top2;
    float shi = (hi >= n - 1) ? top1 : top2;
    return slo + (shi - slo) * frac;
}

// ---------------- K1: angles+bins inline, fused+normalize, 2 bf16 planes -----
// R17 lesson: the counting sort (old k0) was only an emission-grouping
// optimization — never needed for correctness. Deleted: k1 computes angle/bin
// inline (each query handled exactly once), stores planes in ORIGINAL order.
// by==0 blocks also zero segBest/counters (stream-ordered before k2).
__global__ void k1_prep(const float4* __restrict__ qf, const float4* __restrict__ W,
                        const float* __restrict__ pa, float* __restrict__ anglesO,
                        int* __restrict__ binsO, ushortT* __restrict__ nqB,
                        u64* __restrict__ segBest, u32* __restrict__ bcnt) {
    int b = blockIdx.x;
    int t = threadIdx.x;
    int w = t >> 6, lane = t & 63;
    int q = blockIdx.y * 4 + w;  // grid.y = 225, 900 = 4*225

    if (blockIdx.y == 0) {
        for (int s = t; s < NB2; s += 256) segBest[(size_t)b * NB2 + s] = 0ULL;
        if (b == 0 && t < (Bn + 1)) bcnt[t * 16] = 0u;
    }

    float x = pa[(b * Qn + q) * 2 + 0];
    float y = pa[(b * Qn + q) * 2 + 1];
    float a = atan2f(y, x);
    if (a < 0.f) a += TWO_PI_F;
    int bin = (int)(a / BIN_SIZE_F);
    bin = bin < 0 ? 0 : (bin > NBINS - 1 ? NBINS - 1 : bin);
    if (lane == 0) {
        anglesO[b * Qn + q] = a;
        binsO[b * Qn + q] = bin;
    }

    float4 v = qf[(size_t)(b * Qn + q) * (Hn / 4) + lane];
    float4 wv = W[(size_t)bin * (Hn / 4) + lane];
    v.x += wv.x; v.y += wv.y; v.z += wv.z; v.w += wv.w;
    float ss = v.x * v.x + v.y * v.y + v.z * v.z + v.w * v.w;
    #pragma unroll
    for (int off = 32; off >= 1; off >>= 1) ss += __shfl_xor(ss, off, 64);
    float sc = 1.f / fmaxf(sqrtf(ss), 1e-12f);
    float xs[4] = {v.x * sc, v.y * sc, v.z * sc, v.w * sc};
    ushort4 p0, p1;
    ushortT* h0 = (ushortT*)&p0; ushortT* h1 = (ushortT*)&p1;
    #pragma unroll
    for (int c = 0; c < 4; c++) {
        float f0, f1;
        h0[c] = bf16rne(xs[c], f0);
        float r1 = xs[c] - f0;
        h1[c] = bf16rne(r1, f1);
    }
    size_t base = ((size_t)(b * Qn + q)) * Hn + lane * 4;
    *(ushort4*)(nqB + 0 * PS + base) = p0;
    *(ushort4*)(nqB + 1 * PS + base) = p1;
}

// ---------------- K2: MFMA pair-sim GEMM + segment argmax + fused k3 tail ----
// R16 config (proven 138.8us): (256,4), XCD-local decode, per-line counters,
// RELAXED per-batch counter, register-resident tail. Unsorted rows: emission
// indices are structural (io=sr, jo=sc, sr<sc) — rois/cois deleted; ungrouped
// LDS atomics cost only ~hundreds of cycles across 32 banks. Bit-identical
// results (same pairs, same k-order, same lex-(i,j) tie-break).
__global__ __launch_bounds__(256, 4) void k2_gemm(
        const ushortT* __restrict__ nqB, const int* __restrict__ binsO,
        u64* __restrict__ segBest, float* __restrict__ topCand,
        const float* __restrict__ anglesO, float* __restrict__ batchRes,
        u32* __restrict__ bcnt, float* __restrict__ out) {
    __shared__ __align__(16) union Sh {
        ushortT stage[4 * 2048];   // 16 KB during K-loop
        u64     segLds[NB2];       // 10.4 KB during emission
        u32     ckeys[NB2];        // 5.2 KB during tail median (disjoint)
    } sh;
    __shared__ int rbins[T64], cbins[T64];
    __shared__ float t4w[16];
    __shared__ int redI[4];
    __shared__ float redF[4];
    __shared__ u32 redU[4];
    __shared__ float red2[8];
    __shared__ int mcnt, shLast;
    __shared__ float sth2;

    int lin = blockIdx.x;
    int xcd = lin & 7;
    int slot = lin >> 3;                 // 0..239
    int b = xcd * 2 + (slot >= NP64 ? 1 : 0);
    int tp = (slot >= NP64) ? slot - NP64 : slot;
    int ti = 0, rem = tp;
    while (rem >= NTILE64 - ti) { rem -= NTILE64 - ti; ti++; }
    int tj = ti + rem;
    int rowBase = ti * T64, colBase = tj * T64;
    int t = threadIdx.x;
    int w = t >> 6, lane = t & 63;
    int wrow = w >> 1, wcol = w & 1;
    int lq = lane >> 4, lm = lane & 15;

    if (t < T64) {
        int sr = rowBase + t, sc = colBase + t;
        rbins[t] = (sr < Qn) ? binsO[b * Qn + sr] : 0;
        cbins[t] = (sc < Qn) ? binsO[b * Qn + sc] : 0;
    }

    f32x4 acc[2][2];
    #pragma unroll
    for (int i = 0; i < 2; i++)
        #pragma unroll
        for (int j = 0; j < 2; j++) acc[i][j] = (f32x4){0.f, 0.f, 0.f, 0.f};

    u32 goff[4];
    int loff[4];
    #pragma unroll
    for (int i = 0; i < 4; i++) {
        int p = i & 1;                       // plane
        int sideB = i >> 1;                  // 0 = A rows, 1 = B rows
        int row = t >> 2;
        int udata = (t & 3) ^ ((t >> 3) & 3);
        int gq = (sideB ? colBase : rowBase) + row;
        if (gq >= Qn) gq = Qn - 1;
        goff[i] = (u32)(p * (u32)PS) + (u32)(b * Qn + gq) * Hn + (u32)(udata * 8);
        loff[i] = i * 2048 + t * 8;
    }
    int aswz = (lq ^ ((lm >> 1) & 3)) * 8;   // swizzled 16B-unit offset

    for (int kc = 0; kc < Hn; kc += 32) {
        #pragma unroll
        for (int i = 0; i < 4; i++)
            gl_lds16(nqB + goff[i] + kc, &sh.stage[loff[i]]);
        __syncthreads();   // vmcnt(0) drain before barrier

        short8 af[2][2];
        #pragma unroll
        for (int p = 0; p < 2; p++)
            #pragma unroll
            for (int mt = 0; mt < 2; mt++)
                af[p][mt] = *(const short8*)&sh.stage[p * 2048 + (wrow * 32 + mt * 16 + lm) * 32 + aswz];

        #pragma unroll
        for (int nt = 0; nt < 2; nt++) {
            int coff = (wcol * 32 + nt * 16 + lm) * 32 + aswz;
            short8 b0 = *(const short8*)&sh.stage[2 * 2048 + coff];
            short8 b1 = *(const short8*)&sh.stage[3 * 2048 + coff];
            #pragma unroll
            for (int mt = 0; mt < 2; mt++) {
                f32x4 c = acc[mt][nt];
                c = __builtin_amdgcn_mfma_f32_16x16x32_bf16(af[0][mt], b0, c, 0, 0, 0);
                c = __builtin_amdgcn_mfma_f32_16x16x32_bf16(af[0][mt], b1, c, 0, 0, 0);
                c = __builtin_amdgcn_mfma_f32_16x16x32_bf16(af[1][mt], b0, c, 0, 0, 0);
                c = __builtin_amdgcn_mfma_f32_16x16x32_bf16(af[1][mt], b1, c, 0, 0, 0);
                acc[mt][nt] = c;
            }
        }
        __syncthreads();   // frag reads done before next chunk's DMA writes
    }

    // ---- repurpose stage memory as segLds; zero it ----
    for (int s = t; s < NB2; s += 256) sh.segLds[s] = 0ULL;
    __syncthreads();

    // ---- emission: C/D layout col=lm, row=lq*4+reg (m89-verified).
    //      Unsorted: io=sr, jo=sc with sr<sc structural. ----
    float t4[4] = {-3e38f, -3e38f, -3e38f, -3e38f};
    int curSeg = -1; u64 curBest = 0ULL;
    #pragma unroll
    for (int mt = 0; mt < 2; mt++) {
        #pragma unroll
        for (int r = 0; r < 4; r++) {
            int lrr = wrow * 32 + mt * 16 + lq * 4 + r;
            int sr = rowBase + lrr;
            int bi = rbins[lrr];
            #pragma unroll
            for (int nt = 0; nt < 2; nt++) {
                int lcc = wcol * 32 + nt * 16 + lm;
                int sc = colBase + lcc;
                bool ok = (sr < Qn) && (sc < Qn) && (sr < sc);
                if (ok) {
                    float v = acc[mt][nt][r];
                    ins4(t4, v);
                    int bj = cbins[lcc];
                    int bmin = bi < bj ? bi : bj, bmax = bi < bj ? bj : bi;
                    int seg = bmin * NBINS + bmax;
                    u64 packed = ((u64)fkey(v) << 32) | (u32)(~(((u32)sr << 10) | (u32)sc));
                    if (seg == curSeg) { if (packed > curBest) curBest = packed; }
                    else {
                        if (curSeg >= 0) atomicMax(&sh.segLds[curSeg], curBest);
                        curSeg = seg; curBest = packed;
                    }
                }
            }
        }
    }
    if (curSeg >= 0) atomicMax(&sh.segLds[curSeg], curBest);

    // wave-level top4 shuffle merge
    #pragma unroll
    for (int off = 32; off >= 1; off >>= 1) {
        float o0 = __shfl_xor(t4[0], off, 64);
        float o1 = __shfl_xor(t4[1], off, 64);
        float o2 = __shfl_xor(t4[2], off, 64);
        float o3 = __shfl_xor(t4[3], off, 64);
        ins4(t4, o0); ins4(t4, o1); ins4(t4, o2); ins4(t4, o3);
    }
    if (lane == 0) {
        t4w[w * 4 + 0] = t4[0]; t4w[w * 4 + 1] = t4[1];
        t4w[w * 4 + 2] = t4[2]; t4w[w * 4 + 3] = t4[3];
    }
    __syncthreads();

    for (int s = t; s < NB2; s += 256) {
        u64 v = sh.segLds[s];
        if (v) atomicMax(&segBest[(size_t)b * NB2 + s], v);
    }
    if (t == 0) {
        #pragma unroll
        for (int ww = 1; ww < 4; ww++) {
            ins4(t4, t4w[ww * 4 + 0]); ins4(t4, t4w[ww * 4 + 1]);
            ins4(t4, t4w[ww * 4 + 2]); ins4(t4, t4w[ww * 4 + 3]);
        }
        float* dst = topCand + (size_t)(b * NP64 + tp) * 4;
        #pragma unroll
        for (int c = 0; c < 4; c++)
            __hip_atomic_store(&dst[c], t4[c], __ATOMIC_RELAXED, __HIP_MEMORY_SCOPE_AGENT);
    }

    // ---- per-batch completion; last block runs the scalar tail inline ----
    __syncthreads();   // drains vmcnt(0): segBest atomics + topCand stores done
    if (t == 0) {
        u32 done = __hip_atomic_fetch_add(&bcnt[b * 16], 1u, __ATOMIC_RELAXED,
                                          __HIP_MEMORY_SCOPE_AGENT);
        shLast = (done == NP64 - 1) ? 1 : 0;
    }
    __syncthreads();
    if (!shLast) return;

    // ====== inline k3 tail: register-resident (NSLOT=6 segments/thread) ======
    float rval[NSLOT], rd[NSLOT];
    u32 rcode[NSLOT];
    bool rvalid[NSLOT], rmF[NSLOT];
    #pragma unroll
    for (int k = 0; k < NSLOT; k++) {
        int s = t + k * 256;
        rvalid[k] = false; rval[k] = 0.f; rd[k] = 0.f; rcode[k] = 0u; rmF[k] = false;
        if (s < NB2) {
            u64 p = __hip_atomic_load(&segBest[(size_t)b * NB2 + s],
                                      __ATOMIC_RELAXED, __HIP_MEMORY_SCOPE_AGENT);
            if (p != 0ULL) {
                rvalid[k] = true;
                rval[k] = unfkey((u32)(p >> 32));
                rcode[k] = ~((u32)p);
                int i = (rcode[k] >> 10) & 1023, j = rcode[k] & 1023;
                float ai = anglesO[b * Qn + i], aj = anglesO[b * Qn + j];
                rd[k] = circdist(ai, aj);
            }
        }
    }

    // S + top2 of valid sims -> thr
    int Sv = 0;
    float m1 = -3e38f, m2 = -3e38f;
    #pragma unroll
    for (int k = 0; k < NSLOT; k++)
        if (rvalid[k]) { Sv++; ins2(m1, m2, rval[k]); }
    int S = bSumI(Sv, redI);
    float top1, top2v;
    bTop2(m1, m2, red2, top1, top2v);
    float thr = (S == 0) ? BIGV : quantTop2(top1, top2v, S);

    int c1v = 0;
    #pragma unroll
    for (int k = 0; k < NSLOT; k++)
        if (rvalid[k] && rval[k] > thr) c1v++;
    int c1 = bSumI(c1v, redI);

    // th2 = 4th-largest pair sim (wave 0 merges all blocks' top4s)
    if (t < 64) {
        float t4l[4] = {-3e38f, -3e38f, -3e38f, -3e38f};
        for (int i = t; i < NP64 * 4; i += 64)
            ins4(t4l, __hip_atomic_load(&topCand[(size_t)b * NP64 * 4 + i],
                                        __ATOMIC_RELAXED, __HIP_MEMORY_SCOPE_AGENT));
        #pragma unroll
        for (int off = 32; off >= 1; off >>= 1) {
            float o0 = __shfl_xor(t4l[0], off, 64);
            float o1 = __shfl_xor(t4l[1], off, 64);
            float o2 = __shfl_xor(t4l[2], off, 64);
            float o3 = __shfl_xor(t4l[3], off, 64);
            ins4(t4l, o0); ins4(t4l, o1); ins4(t4l, o2); ins4(t4l, o3);
        }
        if (t == 0) sth2 = t4l[3];
    }
    __syncthreads();
    float th2 = sth2;

    bool use_fb = (c1 < 2);
    int cv = 0;
    #pragma unroll
    for (int k = 0; k < NSLOT; k++) {
        bool mF = use_fb ? (rvalid[k] && rval[k] >= th2)
                         : (rvalid[k] && rval[k] > thr);
        rmF[k] = mF;
        cv += mF ? 1 : 0;
    }
    int cnt = bSumI(cv, redI);

    // median of masked d: compact into LDS ckeys + rank select
    if (t == 0) mcnt = 0;
    __syncthreads();
    #pragma unroll
    for (int k = 0; k < NSLOT; k++) {
        bool pred = rmF[k];
        u32 key = fkey(rd[k]);
        u64 bal = __ballot(pred);
        int prefix = __popcll(bal & ((1ULL << lane) - 1ULL));
        int tot = __popcll(bal);
        int base = 0;
        if (lane == 0) base = tot ? atomicAdd(&mcnt, tot) : 0;
        base = __shfl(base, 0, 64);
        if (pred) sh.ckeys[base + prefix] = key;
    }
    __syncthreads();
    int m2c = mcnt;

    float med;
    if (cnt == 0) med = BIGV;
    else {
        int midx = (cnt - 1) >> 1;
        med = unfkey(selRank(sh.ckeys, m2c, midx, redU));
    }
    float alpha = fminf(fmaxf(med, PI_F / (float)NBINS), HALF_PI_F);

    // coop stats + comp count/top2 in one pass (angles reloaded from L2)
    int ncoopv = 0, ncompv = 0; float coopv = 0.f;
    float c1m = -3e38f, c2m = -3e38f;
    #pragma unroll
    for (int k = 0; k < NSLOT; k++) {
        if (!rmF[k]) continue;
        if (rd[k] <= alpha) {
            ncoopv++;
            int i = (rcode[k] >> 10) & 1023, j = rcode[k] & 1023;
            float ai = anglesO[b * Qn + i], aj = anglesO[b * Qn + j];
            float mm = atan2f((sinf(ai) + sinf(aj)) * 0.5f, (cosf(ai) + cosf(aj)) * 0.5f);
            float d1 = circdist(ai, mm), d2 = circdist(aj, mm);
            coopv += d1 * d1 + d2 * d2;
        } else {
            ncompv++;
            ins2(c1m, c2m, rval[k]);
        }
    }
    int ncoop = bSumI(ncoopv, redI);
    float coopSum = bSumF(coopv, redF);
    int ncomp = bSumI(ncompv, redI);
    float ct1, ct2;
    bTop2(c1m, c2m, red2, ct1, ct2);
    float margin = (ncomp == 0) ? BIGV : quantTop2(ct1, ct2, ncomp);

    float compv = 0.f;
    #pragma unroll
    for (int k = 0; k < NSLOT; k++) {
        if (rmF[k] && rd[k] > alpha) {
            float viol = fmaxf(rval[k] - margin, 0.f);
            compv += viol * viol;
        }
    }
    float compSum = bSumF(compv, redF);

    // final combine: last-finished batch reduces all batchRes (16 execs only).
    if (t == 0) {
        float r0 = coopSum / (float)(ncoop > 1 ? ncoop : 1);
        float r1 = compSum / (float)(ncomp > 1 ? ncomp : 1);
        float r2 = cnt > 0 ? 1.f : 0.f;
        __hip_atomic_store(&batchRes[b * 3 + 0], r0, __ATOMIC_RELAXED, __HIP_MEMORY_SCOPE_AGENT);
        __hip_atomic_store(&batchRes[b * 3 + 1], r1, __ATOMIC_RELAXED, __HIP_MEMORY_SCOPE_AGENT);
        __hip_atomic_store(&batchRes[b * 3 + 2], r2, __ATOMIC_RELAXED, __HIP_MEMORY_SCOPE_AGENT);
        u32 doneB = __hip_atomic_fetch_add(&bcnt[Bn * 16], 1u, __ATOMIC_ACQ_REL,
                                           __HIP_MEMORY_SCOPE_AGENT);
        if (doneB == Bn - 1) {
            float cs = 0.f, ps = 0.f, vs = 0.f;
            for (int bb = 0; bb < Bn; bb++) {
                cs += __hip_atomic_load(&batchRes[bb * 3 + 0], __ATOMIC_RELAXED, __HIP_MEMORY_SCOPE_AGENT);
                ps += __hip_atomic_load(&batchRes[bb * 3 + 1], __ATOMIC_RELAXED, __HIP_MEMORY_SCOPE_AGENT);
                vs += __hip_atomic_load(&batchRes[bb * 3 + 2], __ATOMIC_RELAXED, __HIP_MEMORY_SCOPE_AGENT);
            }
            float denom = fmaxf(vs, 1.f);
            out[0] = cs / denom;
            out[1] = ps / denom;
        }
    }
}

extern "C" void kernel_launch(void* const* d_in, const int* in_sizes, int n_in,
                              void* d_out, int out_size, void* d_ws, size_t ws_size,
                              hipStream_t stream) {
    (void)in_sizes; (void)n_in; (void)out_size; (void)ws_size;
    const float* qf = (const float*)d_in[0];
    const float* pa = (const float*)d_in[1];
    const float* W  = (const float*)d_in[2];
    float* out = (float*)d_out;

    char* ws = (char*)d_ws;
    size_t off = 0;
    ushortT* nqB = (ushortT*)(ws + off);  off += 2 * PS * 2;                 // 14.7 MB
    float* anglesO = (float*)(ws + off);  off += (size_t)Bn * Qn * 4;
    int* binsO = (int*)(ws + off);        off += (size_t)Bn * Qn * 4;
    u64* segBest = (u64*)(ws + off);      off += (size_t)Bn * NB2 * 8;
    float* topCand = (float*)(ws + off);  off += (size_t)Bn * NP64 * 4 * 4;
    float* batchRes = (float*)(ws + off); off += (size_t)Bn * 3 * 4;
    u32* bcnt = (u32*)(ws + off);         off += (Bn + 1) * 64;   // 1 line each

    k1_prep<<<dim3(Bn, 225), 256, 0, stream>>>((const float4*)qf, (const float4*)W,
                                               pa, anglesO, binsO, nqB, segBest, bcnt);
    k2_gemm<<<NP64 * Bn, 256, 0, stream>>>(nqB, binsO, segBest, topCand,
                                           anglesO, batchRes, bcnt, out);
}